// Round 2
// baseline (247.829 us; speedup 1.0000x reference)
//
#include <hip/hip_runtime.h>
#include <hip/hip_bf16.h>
#include <cstdint>

constexpr int NB = 256;   // batch
constexpr int NT = 512;   // frames
constexpr int ND = 512;   // dim

typedef __attribute__((ext_vector_type(8))) short bf16x8;
typedef __attribute__((ext_vector_type(4))) float f32x4;
typedef __attribute__((ext_vector_type(4))) unsigned int u32x4;

__device__ __forceinline__ float wred_sum(float v){
#pragma unroll
  for (int m = 32; m > 0; m >>= 1) v += __shfl_xor(v, m, 64);
  return v;
}
// f32 -> bf16 round-to-nearest-even
__device__ __forceinline__ unsigned short f2bf(float f){
  unsigned int u = __builtin_bit_cast(unsigned int, f);
  u = u + 0x7fffu + ((u >> 16) & 1u);
  return (unsigned short)(u >> 16);
}

// K0: sentence norms -> normalized bf16 rows + 1/norm
__global__ __launch_bounds__(256) void k_sent(const float* __restrict__ s,
                                              unsigned short* __restrict__ sb,
                                              float* __restrict__ sinv){
  int row  = blockIdx.x * 4 + (threadIdx.x >> 6);
  int lane = threadIdx.x & 63;
  const float* sr = s + (size_t)row * ND;
  float x[8]; float ss = 0.f;
#pragma unroll
  for (int e = 0; e < 8; e++){ x[e] = sr[lane + e*64]; ss += x[e]*x[e]; }
  ss = wred_sum(ss);
  float inv = 1.0f / fmaxf(sqrtf(ss), 1e-8f);
#pragma unroll
  for (int e = 0; e < 8; e++) sb[(size_t)row*ND + lane + e*64] = f2bf(x[e]*inv);
  if (lane == 0) sinv[row] = inv;
}

// Fused: batched GEMM (j x t, full K) + per-(b,t) norm computed during staging
// + masked softmax over full t in epilogue + f32 diag for the argmax path.
// Tile: 64(j) x 512(t) per block, one b per block, BK=64, 8 waves (2j x 4t),
// 16x16x32 bf16 MFMA. vinv applied to the f32 accumulator (B staged unnormalized).
__global__ __launch_bounds__(512, 2) void k_gemm_sm(
    const unsigned short* __restrict__ sb,   // normalized sentences, bf16
    const float* __restrict__ sent,          // raw sentences, f32
    const float* __restrict__ sinv,
    const float* __restrict__ video,
    const int* __restrict__ lens,
    float* __restrict__ out0,
    float* __restrict__ diag){
  const int tid  = threadIdx.x;
  const int lane = tid & 63;
  const int w    = tid >> 6;
  const int wj   = w >> 2;      // 0..1
  const int wt   = w & 3;       // 0..3

  // XCD-grouped decode: blocks sharing b get identical (blockIdx & 7) -> same XCD L2
  const int D  = blockIdx.x;
  const int x8 = D & 7;
  const int r0 = D >> 3;
  const int s  = r0 & 3;        // j-tile 0..3
  const int b  = (r0 >> 2) * 8 + x8;
  const int jt = s * 64;

  __shared__ __align__(16) unsigned short As[64*64];   // 8 KB
  __shared__ __align__(16) unsigned short Bs[NT*64];   // 64 KB
  __shared__ float sRow[ND];                           // 2 KB (raw sentence b)
  __shared__ float vinvS[NT];                          // 2 KB
  __shared__ float redM[64*4];                         // 1 KB
  __shared__ float redS[64*4];                         // 1 KB

  sRow[tid] = sent[(size_t)b*ND + tid];

  const int m = tid >> 3;   // 0..63
  const int g = tid & 7;    // 0..7

  float ssq[8] = {}, dtt[8] = {};
  f32x4 acc[2][8] = {};

  const size_t vbase = (size_t)b * NT * ND;
  const size_t abase = (size_t)jt * ND;

  __syncthreads();

  for (int k0 = 0; k0 < ND; k0 += 64){
    // stage A (bf16 sentence tile)
    {
      u32x4 d = *reinterpret_cast<const u32x4*>(sb + abase + (size_t)m*ND + k0 + g*8);
      *reinterpret_cast<u32x4*>(reinterpret_cast<char*>(As) + m*128 + ((g ^ (m&7))<<4)) = d;
    }
    // stage B (video f32 -> bf16, unnormalized) + ssq + diag-dot side-products
    f32x4 sr0 = *reinterpret_cast<const f32x4*>(&sRow[k0 + g*8]);
    f32x4 sr1 = *reinterpret_cast<const f32x4*>(&sRow[k0 + g*8 + 4]);
#pragma unroll
    for (int c = 0; c < 8; c++){
      int row = c*64 + m;
      const float* src = video + vbase + (size_t)row*ND + k0 + g*8;
      f32x4 x0 = *reinterpret_cast<const f32x4*>(src);
      f32x4 x1 = *reinterpret_cast<const f32x4*>(src + 4);
      float sq = 0.f, dp = 0.f;
#pragma unroll
      for (int i = 0; i < 4; i++){
        sq += x0[i]*x0[i] + x1[i]*x1[i];
        dp += x0[i]*sr0[i] + x1[i]*sr1[i];
      }
      ssq[c] += sq; dtt[c] += dp;
      u32x4 d;
      d[0] = f2bf(x0[0]) | ((unsigned)f2bf(x0[1]) << 16);
      d[1] = f2bf(x0[2]) | ((unsigned)f2bf(x0[3]) << 16);
      d[2] = f2bf(x1[0]) | ((unsigned)f2bf(x1[1]) << 16);
      d[3] = f2bf(x1[2]) | ((unsigned)f2bf(x1[3]) << 16);
      *reinterpret_cast<u32x4*>(reinterpret_cast<char*>(Bs) + row*128 + ((g ^ (row&7))<<4)) = d;
    }
    __syncthreads();
    // MFMA
#pragma unroll
    for (int ks = 0; ks < 2; ks++){
      const int gr = ks*4 + (lane>>4);
      bf16x8 af[2], bg[8];
#pragma unroll
      for (int f = 0; f < 2; f++){
        int row = wj*32 + f*16 + (lane&15);
        af[f] = *reinterpret_cast<const bf16x8*>(reinterpret_cast<const char*>(As) + row*128 + ((gr ^ (row&7))<<4));
      }
#pragma unroll
      for (int f = 0; f < 8; f++){
        int row = wt*128 + f*16 + (lane&15);
        bg[f] = *reinterpret_cast<const bf16x8*>(reinterpret_cast<const char*>(Bs) + row*128 + ((gr ^ (row&7))<<4));
      }
#pragma unroll
      for (int fi = 0; fi < 2; fi++)
#pragma unroll
        for (int fj = 0; fj < 8; fj++)
          acc[fi][fj] = __builtin_amdgcn_mfma_f32_16x16x32_bf16(af[fi], bg[fj], acc[fi][fj], 0, 0, 0);
    }
    __syncthreads();
  }

  // ---- finalize per-t norms + diag (f32) ----
#pragma unroll
  for (int c = 0; c < 8; c++){
#pragma unroll
    for (int msk = 1; msk <= 4; msk <<= 1){
      ssq[c] += __shfl_xor(ssq[c], msk, 64);
      dtt[c] += __shfl_xor(dtt[c], msk, 64);
    }
  }
  float sinv_b = sinv[b];
  if (g == 0){
#pragma unroll
    for (int c = 0; c < 8; c++){
      int row = c*64 + m;
      float inv = 1.0f / fmaxf(sqrtf(ssq[c]), 1e-8f);
      vinvS[row] = inv;
      if (jt == 0) diag[(size_t)b*NT + row] = dtt[c] * inv * sinv_b;
    }
  }
  __syncthreads();

  // ---- masked softmax over t (full 512 per j-row) ----
  const int len = lens[b];
  const int q  = lane >> 4;
  const int tl = lane & 15;
  const float NEGINF = -__builtin_inff();

  float mx[2][4];
#pragma unroll
  for (int fi = 0; fi < 2; fi++)
#pragma unroll
    for (int rr = 0; rr < 4; rr++) mx[fi][rr] = NEGINF;

#pragma unroll
  for (int fi = 0; fi < 2; fi++)
#pragma unroll
    for (int fj = 0; fj < 8; fj++){
      int t = wt*128 + fj*16 + tl;
      float vi = vinvS[t];
      bool ok = t < len;
#pragma unroll
      for (int rr = 0; rr < 4; rr++){
        float v = ok ? acc[fi][fj][rr]*vi : NEGINF;
        acc[fi][fj][rr] = v;
        mx[fi][rr] = fmaxf(mx[fi][rr], v);
      }
    }
#pragma unroll
  for (int fi = 0; fi < 2; fi++)
#pragma unroll
    for (int rr = 0; rr < 4; rr++)
#pragma unroll
      for (int msk = 1; msk <= 8; msk <<= 1)
        mx[fi][rr] = fmaxf(mx[fi][rr], __shfl_xor(mx[fi][rr], msk, 64));
  if (tl == 0){
#pragma unroll
    for (int fi = 0; fi < 2; fi++)
#pragma unroll
      for (int rr = 0; rr < 4; rr++)
        redM[(wj*32 + fi*16 + q*4 + rr)*4 + wt] = mx[fi][rr];
  }
  __syncthreads();

  float gmx[2][4], sum[2][4];
#pragma unroll
  for (int fi = 0; fi < 2; fi++)
#pragma unroll
    for (int rr = 0; rr < 4; rr++){
      int jl = wj*32 + fi*16 + q*4 + rr;
      gmx[fi][rr] = fmaxf(fmaxf(redM[jl*4+0], redM[jl*4+1]),
                          fmaxf(redM[jl*4+2], redM[jl*4+3]));
      sum[fi][rr] = 0.f;
    }
#pragma unroll
  for (int fi = 0; fi < 2; fi++)
#pragma unroll
    for (int fj = 0; fj < 8; fj++)
#pragma unroll
      for (int rr = 0; rr < 4; rr++){
        float e = __expf(acc[fi][fj][rr] - gmx[fi][rr]);  // exp(-inf)=0 for masked
        acc[fi][fj][rr] = e;
        sum[fi][rr] += e;
      }
#pragma unroll
  for (int fi = 0; fi < 2; fi++)
#pragma unroll
    for (int rr = 0; rr < 4; rr++)
#pragma unroll
      for (int msk = 1; msk <= 8; msk <<= 1)
        sum[fi][rr] += __shfl_xor(sum[fi][rr], msk, 64);
  if (tl == 0){
#pragma unroll
    for (int fi = 0; fi < 2; fi++)
#pragma unroll
      for (int rr = 0; rr < 4; rr++)
        redS[(wj*32 + fi*16 + q*4 + rr)*4 + wt] = sum[fi][rr];
  }
  __syncthreads();

#pragma unroll
  for (int fi = 0; fi < 2; fi++)
#pragma unroll
    for (int rr = 0; rr < 4; rr++){
      int jl = wj*32 + fi*16 + q*4 + rr;
      float tot = (redS[jl*4+0] + redS[jl*4+1]) + (redS[jl*4+2] + redS[jl*4+3]);
      float iv = 1.0f / tot;
      int j = jt + jl;
      float* orow = out0 + ((size_t)b*NB + j)*NT + wt*128 + tl;
#pragma unroll
      for (int fj = 0; fj < 8; fj++)
        orow[fj*16] = acc[fi][fj][rr]*iv;
    }
}

// argmax over valid t of diag (first-index tie-break) + copy chosen frame row
__global__ __launch_bounds__(256) void k_argmax(const float* __restrict__ video,
                                                const int* __restrict__ lens,
                                                const float* __restrict__ diag,
                                                float* __restrict__ o1){
  int b = blockIdx.x;
  int tid = threadIdx.x;
  int len = lens[b];
  __shared__ float sv[256];
  __shared__ int   si[256];
  const float* dg = diag + (size_t)b * NT;
  float v1 = (tid       < len) ? dg[tid]       : -__builtin_inff();
  float v2 = (tid + 256 < len) ? dg[tid + 256] : -__builtin_inff();
  float bv; int bi;
  if (v2 > v1){ bv = v2; bi = tid + 256; } else { bv = v1; bi = tid; }
  sv[tid] = bv; si[tid] = bi;
  __syncthreads();
  for (int sN = 128; sN > 0; sN >>= 1){
    if (tid < sN){
      float ov = sv[tid+sN]; int oi = si[tid+sN];
      if (ov > sv[tid] || (ov == sv[tid] && oi < si[tid])){ sv[tid] = ov; si[tid] = oi; }
    }
    __syncthreads();
  }
  int best = si[0];
  const float* src = video + ((size_t)b * NT + best) * ND;
  o1[(size_t)b * ND + tid]       = src[tid];
  o1[(size_t)b * ND + tid + 256] = src[tid + 256];
}

extern "C" void kernel_launch(void* const* d_in, const int* in_sizes, int n_in,
                              void* d_out, int out_size, void* d_ws, size_t ws_size,
                              hipStream_t stream){
  const float* video = (const float*)d_in[0];
  const float* sent  = (const float*)d_in[1];
  const int*   lens  = (const int*)d_in[2];
  float* out0 = (float*)d_out;
  float* out1 = out0 + (size_t)NB*NB*NT;

  char* ws = (char*)d_ws;
  unsigned short* sb = (unsigned short*)ws;            // 262144 B
  float* sinv  = (float*)(ws + 262144);                // 1024 B
  float* diagw = (float*)(ws + 263168);                // 512*256*4 = 524288 B

  k_sent   <<<NB/4, 256, 0, stream>>>(sent, sb, sinv);
  k_gemm_sm<<<NB*4, 512, 0, stream>>>(sb, sent, sinv, video, lens, out0, diagw);
  k_argmax <<<NB,   256, 0, stream>>>(video, lens, diagw, out1);
}

// Round 3
// 202.820 us; speedup vs baseline: 1.2219x; 1.2219x over previous
//
#include <hip/hip_runtime.h>
#include <hip/hip_bf16.h>
#include <cstdint>

constexpr int NB = 256;   // batch
constexpr int NT = 512;   // frames
constexpr int ND = 512;   // dim

typedef __attribute__((ext_vector_type(8))) short bf16x8;
typedef __attribute__((ext_vector_type(4))) float f32x4;
typedef __attribute__((ext_vector_type(4))) unsigned int u32x4;
typedef __attribute__((ext_vector_type(2))) unsigned int u32x2;

__device__ __forceinline__ float wred_sum(float v){
#pragma unroll
  for (int m = 32; m > 0; m >>= 1) v += __shfl_xor(v, m, 64);
  return v;
}
// f32 -> bf16 round-to-nearest-even
__device__ __forceinline__ unsigned int f2bf(float f){
  unsigned int u = __builtin_bit_cast(unsigned int, f);
  u = u + 0x7fffu + ((u >> 16) & 1u);
  return (u >> 16);
}

// K0: sentence norms -> normalized bf16 rows + 1/norm
__global__ __launch_bounds__(256) void k_sent(const float* __restrict__ s,
                                              unsigned short* __restrict__ sb,
                                              float* __restrict__ sinv){
  int row  = blockIdx.x * 4 + (threadIdx.x >> 6);
  int lane = threadIdx.x & 63;
  const float* sr = s + (size_t)row * ND;
  float x[8]; float ss = 0.f;
#pragma unroll
  for (int e = 0; e < 8; e++){ x[e] = sr[lane + e*64]; ss += x[e]*x[e]; }
  ss = wred_sum(ss);
  float inv = 1.0f / fmaxf(sqrtf(ss), 1e-8f);
#pragma unroll
  for (int e = 0; e < 8; e++)
    sb[(size_t)row*ND + lane + e*64] = (unsigned short)f2bf(x[e]*inv);
  if (lane == 0) sinv[row] = inv;
}

// Fused GEMM (64j x 512t per block, one b) + per-t norm + masked softmax + f32 diag.
// BK=32, 16 K-steps, register-pipelined staging (issue next-step loads before MFMA).
// LDS rows padded to 80 B (period-8 bank map, conflict-free b128).
__global__ __launch_bounds__(512, 4) void k_gemm_sm(
    const unsigned short* __restrict__ sb,   // normalized sentences, bf16
    const float* __restrict__ sent,          // raw sentences, f32
    const float* __restrict__ sinv,
    const float* __restrict__ video,
    const int* __restrict__ lens,
    float* __restrict__ out0,
    float* __restrict__ diag){
  const int tid  = threadIdx.x;
  const int lane = tid & 63;
  const int w    = tid >> 6;
  const int wj   = w >> 2;      // 0..1
  const int wt   = w & 3;       // 0..3

  // XCD-grouped decode: the 4 j-tile blocks of one b share (blockIdx & 7) -> same XCD L2
  const int D  = blockIdx.x;
  const int x8 = D & 7;
  const int r0 = D >> 3;
  const int s  = r0 & 3;        // j-tile 0..3
  const int b  = (r0 >> 2) * 8 + x8;
  const int jt = s * 64;

  __shared__ __align__(16) char As[64 * 80];     //  5 KB (64j x 32k bf16, pad 16B)
  __shared__ __align__(16) char Bs[NT * 80];     // 40 KB (512t x 32k bf16, pad 16B)
  __shared__ float sRow[ND];                     //  2 KB raw sentence b
  __shared__ float vinvS[NT];                    //  2 KB
  __shared__ float redM[64*4];                   //  1 KB
  __shared__ float redS[64*4];                   //  1 KB

  sRow[tid] = sent[(size_t)b*ND + tid];

  const size_t vbase = (size_t)b * NT * ND;
  const float* vsrc  = video + vbase + (size_t)tid * ND;      // this thread's t-row
  const unsigned short* asrc = sb + (size_t)(jt + (tid>>3)) * ND + (tid&7)*4;

  float ssq = 0.f, dtt = 0.f;
  f32x4 acc[2][8] = {};
  f32x4 rb[8];
  u32x2 ra;

  // prologue: issue K-step 0 loads
#pragma unroll
  for (int i = 0; i < 8; i++) rb[i] = *reinterpret_cast<const f32x4*>(vsrc + i*4);
  ra = *reinterpret_cast<const u32x2*>(asrc);

  char* browp = Bs + tid*80;
  char* arowp = As + (tid>>3)*80 + (tid&7)*8;

  for (int step = 0; step < 16; ++step){
    const int k0 = step * 32;
    __syncthreads();   // previous MFMA done reading LDS (no-op effect at step 0)

    // ---- consume rb/ra: side-products + cvt + LDS write ----
    {
      float sq = 0.f, dp = 0.f;
#pragma unroll
      for (int i = 0; i < 8; i++){
        f32x4 s4 = *reinterpret_cast<const f32x4*>(&sRow[k0 + i*4]);
#pragma unroll
        for (int j = 0; j < 4; j++){
          float x = rb[i][j];
          sq += x*x; dp += x*s4[j];
        }
      }
      ssq += sq; dtt += dp;
#pragma unroll
      for (int gi = 0; gi < 4; gi++){
        u32x4 d;
        d[0] = f2bf(rb[2*gi  ][0]) | (f2bf(rb[2*gi  ][1]) << 16);
        d[1] = f2bf(rb[2*gi  ][2]) | (f2bf(rb[2*gi  ][3]) << 16);
        d[2] = f2bf(rb[2*gi+1][0]) | (f2bf(rb[2*gi+1][1]) << 16);
        d[3] = f2bf(rb[2*gi+1][2]) | (f2bf(rb[2*gi+1][3]) << 16);
        *reinterpret_cast<u32x4*>(browp + gi*16) = d;
      }
      *reinterpret_cast<u32x2*>(arowp) = ra;
    }

    // ---- issue next step's loads (in flight across MFMA + barriers) ----
    if (step < 15){
      const int kn = k0 + 32;
#pragma unroll
      for (int i = 0; i < 8; i++) rb[i] = *reinterpret_cast<const f32x4*>(vsrc + kn + i*4);
      ra = *reinterpret_cast<const u32x2*>(asrc + kn);
    }

    __syncthreads();   // LDS tile ready

    // ---- MFMA ----
    {
      const int q  = lane >> 4;
      const int rl = lane & 15;
      bf16x8 af0 = *reinterpret_cast<const bf16x8*>(As + (wj*32 +      rl)*80 + q*16);
      bf16x8 af1 = *reinterpret_cast<const bf16x8*>(As + (wj*32 + 16 + rl)*80 + q*16);
#pragma unroll
      for (int fj = 0; fj < 8; fj++){
        bf16x8 bg = *reinterpret_cast<const bf16x8*>(Bs + (wt*128 + fj*16 + rl)*80 + q*16);
        acc[0][fj] = __builtin_amdgcn_mfma_f32_16x16x32_bf16(af0, bg, acc[0][fj], 0, 0, 0);
        acc[1][fj] = __builtin_amdgcn_mfma_f32_16x16x32_bf16(af1, bg, acc[1][fj], 0, 0, 0);
      }
    }
  }

  // ---- per-t norm + f32 diag (thread owns row t=tid entirely) ----
  {
    float inv = 1.0f / fmaxf(sqrtf(ssq), 1e-8f);
    vinvS[tid] = inv;
    if (jt == 0) diag[(size_t)b*NT + tid] = dtt * inv * sinv[b];
  }
  __syncthreads();

  // ---- masked softmax over t (full 512 per j-row) ----
  const int len = lens[b];
  const int q  = lane >> 4;
  const int tl = lane & 15;
  const float NEGINF = -__builtin_inff();

  float mx[2][4];
#pragma unroll
  for (int fi = 0; fi < 2; fi++)
#pragma unroll
    for (int rr = 0; rr < 4; rr++) mx[fi][rr] = NEGINF;

#pragma unroll
  for (int fi = 0; fi < 2; fi++)
#pragma unroll
    for (int fj = 0; fj < 8; fj++){
      int t = wt*128 + fj*16 + tl;
      float vi = vinvS[t];
      bool ok = t < len;
#pragma unroll
      for (int rr = 0; rr < 4; rr++){
        float v = ok ? acc[fi][fj][rr]*vi : NEGINF;
        acc[fi][fj][rr] = v;
        mx[fi][rr] = fmaxf(mx[fi][rr], v);
      }
    }
#pragma unroll
  for (int fi = 0; fi < 2; fi++)
#pragma unroll
    for (int rr = 0; rr < 4; rr++)
#pragma unroll
      for (int msk = 1; msk <= 8; msk <<= 1)
        mx[fi][rr] = fmaxf(mx[fi][rr], __shfl_xor(mx[fi][rr], msk, 64));
  if (tl == 0){
#pragma unroll
    for (int fi = 0; fi < 2; fi++)
#pragma unroll
      for (int rr = 0; rr < 4; rr++)
        redM[(wj*32 + fi*16 + q*4 + rr)*4 + wt] = mx[fi][rr];
  }
  __syncthreads();

  float gmx[2][4], sum[2][4];
#pragma unroll
  for (int fi = 0; fi < 2; fi++)
#pragma unroll
    for (int rr = 0; rr < 4; rr++){
      int jl = wj*32 + fi*16 + q*4 + rr;
      gmx[fi][rr] = fmaxf(fmaxf(redM[jl*4+0], redM[jl*4+1]),
                          fmaxf(redM[jl*4+2], redM[jl*4+3]));
      sum[fi][rr] = 0.f;
    }
#pragma unroll
  for (int fi = 0; fi < 2; fi++)
#pragma unroll
    for (int fj = 0; fj < 8; fj++)
#pragma unroll
      for (int rr = 0; rr < 4; rr++){
        float e = __expf(acc[fi][fj][rr] - gmx[fi][rr]);  // exp(-inf)=0 for masked
        acc[fi][fj][rr] = e;
        sum[fi][rr] += e;
      }
#pragma unroll
  for (int fi = 0; fi < 2; fi++)
#pragma unroll
    for (int rr = 0; rr < 4; rr++)
#pragma unroll
      for (int msk = 1; msk <= 8; msk <<= 1)
        sum[fi][rr] += __shfl_xor(sum[fi][rr], msk, 64);
  if (tl == 0){
#pragma unroll
    for (int fi = 0; fi < 2; fi++)
#pragma unroll
      for (int rr = 0; rr < 4; rr++)
        redS[(wj*32 + fi*16 + q*4 + rr)*4 + wt] = sum[fi][rr];
  }
  __syncthreads();

#pragma unroll
  for (int fi = 0; fi < 2; fi++)
#pragma unroll
    for (int rr = 0; rr < 4; rr++){
      int jl = wj*32 + fi*16 + q*4 + rr;
      float tot = (redS[jl*4+0] + redS[jl*4+1]) + (redS[jl*4+2] + redS[jl*4+3]);
      float iv = 1.0f / tot;
      int j = jt + jl;
      float* orow = out0 + ((size_t)b*NB + j)*NT + wt*128 + tl;
#pragma unroll
      for (int fj = 0; fj < 8; fj++)
        orow[fj*16] = acc[fi][fj][rr]*iv;
    }
}

// argmax over valid t of diag (first-index tie-break) + copy chosen frame row
__global__ __launch_bounds__(256) void k_argmax(const float* __restrict__ video,
                                                const int* __restrict__ lens,
                                                const float* __restrict__ diag,
                                                float* __restrict__ o1){
  int b = blockIdx.x;
  int tid = threadIdx.x;
  int len = lens[b];
  __shared__ float sv[256];
  __shared__ int   si[256];
  const float* dg = diag + (size_t)b * NT;
  float v1 = (tid       < len) ? dg[tid]       : -__builtin_inff();
  float v2 = (tid + 256 < len) ? dg[tid + 256] : -__builtin_inff();
  float bv; int bi;
  if (v2 > v1){ bv = v2; bi = tid + 256; } else { bv = v1; bi = tid; }
  sv[tid] = bv; si[tid] = bi;
  __syncthreads();
  for (int sN = 128; sN > 0; sN >>= 1){
    if (tid < sN){
      float ov = sv[tid+sN]; int oi = si[tid+sN];
      if (ov > sv[tid] || (ov == sv[tid] && oi < si[tid])){ sv[tid] = ov; si[tid] = oi; }
    }
    __syncthreads();
  }
  int best = si[0];
  const float* src = video + ((size_t)b * NT + best) * ND;
  o1[(size_t)b * ND + tid]       = src[tid];
  o1[(size_t)b * ND + tid + 256] = src[tid + 256];
}

extern "C" void kernel_launch(void* const* d_in, const int* in_sizes, int n_in,
                              void* d_out, int out_size, void* d_ws, size_t ws_size,
                              hipStream_t stream){
  const float* video = (const float*)d_in[0];
  const float* sent  = (const float*)d_in[1];
  const int*   lens  = (const int*)d_in[2];
  float* out0 = (float*)d_out;
  float* out1 = out0 + (size_t)NB*NB*NT;

  char* ws = (char*)d_ws;
  unsigned short* sb = (unsigned short*)ws;            // 262144 B
  float* sinv  = (float*)(ws + 262144);                // 1024 B
  float* diagw = (float*)(ws + 263168);                // 524288 B

  k_sent   <<<NB/4, 256, 0, stream>>>(sent, sb, sinv);
  k_gemm_sm<<<NB*4, 512, 0, stream>>>(sb, sent, sinv, video, lens, out0, diagw);
  k_argmax <<<NB,   256, 0, stream>>>(video, lens, diagw, out1);
}

// Round 4
// 169.015 us; speedup vs baseline: 1.4663x; 1.2000x over previous
//
#include <hip/hip_runtime.h>
#include <hip/hip_bf16.h>
#include <cstdint>

constexpr int NB = 256;   // batch
constexpr int NT = 512;   // frames
constexpr int ND = 512;   // dim

typedef __attribute__((ext_vector_type(8))) short bf16x8;
typedef __attribute__((ext_vector_type(4))) float f32x4;
typedef __attribute__((ext_vector_type(4))) unsigned int u32x4;

__device__ __forceinline__ float wred_sum(float v){
#pragma unroll
  for (int m = 32; m > 0; m >>= 1) v += __shfl_xor(v, m, 64);
  return v;
}
// f32 -> bf16 round-to-nearest-even
__device__ __forceinline__ unsigned int f2bf(float f){
  unsigned int u = __builtin_bit_cast(unsigned int, f);
  u = u + 0x7fffu + ((u >> 16) & 1u);
  return (u >> 16);
}
// async global->LDS, 16B per lane (dest = wave-uniform base + lane*16)
__device__ __forceinline__ void gload_lds16(const void* g, void* l){
  __builtin_amdgcn_global_load_lds(
      (const __attribute__((address_space(1))) unsigned int*)g,
      (__attribute__((address_space(3))) unsigned int*)l, 16, 0, 0);
}

// K0: sentence norms -> normalized bf16 rows + 1/norm
__global__ __launch_bounds__(256) void k_sent(const float* __restrict__ s,
                                              unsigned short* __restrict__ sb,
                                              float* __restrict__ sinv){
  int row  = blockIdx.x * 4 + (threadIdx.x >> 6);
  int lane = threadIdx.x & 63;
  const float* sr = s + (size_t)row * ND;
  float x[8]; float ss = 0.f;
#pragma unroll
  for (int e = 0; e < 8; e++){ x[e] = sr[lane + e*64]; ss += x[e]*x[e]; }
  ss = wred_sum(ss);
  float inv = 1.0f / fmaxf(sqrtf(ss), 1e-8f);
#pragma unroll
  for (int e = 0; e < 8; e++)
    sb[(size_t)row*ND + lane + e*64] = (unsigned short)f2bf(x[e]*inv);
  if (lane == 0) sinv[row] = inv;
}

// K1: stream video once: per (b,t) row compute 1/norm + f32 diag dot,
// write normalized bf16 video row. One wave per row, 4 rows per block (same b).
__global__ __launch_bounds__(256) void k_vnorm(const float* __restrict__ video,
                                               const float* __restrict__ sent,
                                               const float* __restrict__ sinv,
                                               unsigned short* __restrict__ vb16,
                                               float* __restrict__ diag){
  const int tid  = threadIdx.x;
  const int row  = blockIdx.x * 4 + (tid >> 6);   // b*512 + t  (block-uniform b)
  const int lane = tid & 63;
  const int b    = row >> 9;
  __shared__ float sRowS[ND];
  sRowS[tid]       = sent[(size_t)b*ND + tid];
  sRowS[tid + 256] = sent[(size_t)b*ND + 256 + tid];
  __syncthreads();

  const float* vr = video + (size_t)row * ND;
  f32x4 x0 = *reinterpret_cast<const f32x4*>(vr + lane*8);
  f32x4 x1 = *reinterpret_cast<const f32x4*>(vr + lane*8 + 4);
  float ss = 0.f, dp = 0.f;
#pragma unroll
  for (int i = 0; i < 4; i++){
    ss += x0[i]*x0[i] + x1[i]*x1[i];
    dp += x0[i]*sRowS[lane*8 + i] + x1[i]*sRowS[lane*8 + 4 + i];
  }
#pragma unroll
  for (int m = 32; m > 0; m >>= 1){
    ss += __shfl_xor(ss, m, 64);
    dp += __shfl_xor(dp, m, 64);
  }
  float inv = 1.0f / fmaxf(sqrtf(ss), 1e-8f);
  if (lane == 0) diag[row] = dp * inv * sinv[b];
  u32x4 d;
  d[0] = f2bf(x0[0]*inv) | (f2bf(x0[1]*inv) << 16);
  d[1] = f2bf(x0[2]*inv) | (f2bf(x0[3]*inv) << 16);
  d[2] = f2bf(x1[0]*inv) | (f2bf(x1[1]*inv) << 16);
  d[3] = f2bf(x1[2]*inv) | (f2bf(x1[3]*inv) << 16);
  *reinterpret_cast<u32x4*>(vb16 + (size_t)row*ND + lane*8) = d;
}

// K2: pure bf16 GEMM (64j x 512t per block, one b) + fused masked softmax.
// global_load_lds staging (swizzled global source, rule-21 both-sides XOR),
// double-buffered LDS, BK=32, 2-phase pipeline, 8 waves (2j x 4t).
__global__ __launch_bounds__(512, 4) void k_gemm_sm(
    const unsigned short* __restrict__ sb,     // normalized sentences bf16
    const unsigned short* __restrict__ vb16,   // normalized video bf16
    const int* __restrict__ lens,
    float* __restrict__ out0){
  const int tid  = threadIdx.x;
  const int lane = tid & 63;
  const int w    = tid >> 6;
  const int wj   = w >> 2;      // 0..1
  const int wt   = w & 3;       // 0..3

  // XCD-grouped decode: the 4 j-tile blocks of one b share (blockIdx & 7)
  const int D  = blockIdx.x;
  const int x8 = D & 7;
  const int r0 = D >> 3;
  const int s  = r0 & 3;        // j-tile 0..3
  const int b  = (r0 >> 2) * 8 + x8;
  const int jt = s * 64;

  __shared__ __align__(16) unsigned short As[2][64*32];    //  8 KB
  __shared__ __align__(16) unsigned short Bs[2][NT*32];    // 64 KB
  __shared__ float redM[64*4];                             //  1 KB
  __shared__ float redS[64*4];                             //  1 KB

  const unsigned short* vbase = vb16 + (size_t)b * NT * ND;
  // staging: lane's LDS granule g'=(lane&3); fetched global granule g'^((lane>>3)&3)
  const int srow = lane >> 2;                         // row-within-16 block
  const int sgr  = ((lane&3) ^ ((lane>>3)&3)) * 8;    // swizzled k-granule (elems)

  char* AsB = (char*)As;
  char* BsB = (char*)Bs;

  auto STAGE = [&](int buf, int k0){
#pragma unroll
    for (int i = 0; i < 4; i++){
      int grow = w*64 + i*16 + srow;                  // t-row
      gload_lds16(vbase + (size_t)grow*ND + k0 + sgr,
                  BsB + buf*32768 + w*4096 + i*1024 + lane*16);
    }
    if (w < 4){
      int grow = jt + w*16 + srow;                    // j-row
      gload_lds16(sb + (size_t)grow*ND + k0 + sgr,
                  AsB + buf*4096 + w*1024 + lane*16);
    }
  };

  f32x4 acc[2][8] = {};

  STAGE(0, 0);
  asm volatile("s_waitcnt vmcnt(0)" ::: "memory");
  __syncthreads();

  const int rl = lane & 15;
  const int gr = lane >> 4;
  const int goff = ((gr ^ ((rl>>1)&3)) << 4);   // swizzled byte offset of k-granule

  for (int k = 0; k < 16; ++k){
    const int cur = k & 1;
    if (k < 15) STAGE(1-cur, (k+1)*32);
    __builtin_amdgcn_sched_barrier(0);   // keep STAGE issue above the compute phase

    bf16x8 af0 = *reinterpret_cast<const bf16x8*>(AsB + cur*4096 + (wj*32 +      rl)*64 + goff);
    bf16x8 af1 = *reinterpret_cast<const bf16x8*>(AsB + cur*4096 + (wj*32 + 16 + rl)*64 + goff);
#pragma unroll
    for (int fj = 0; fj < 8; fj++){
      bf16x8 bg = *reinterpret_cast<const bf16x8*>(BsB + cur*32768 + (wt*128 + fj*16 + rl)*64 + goff);
      acc[0][fj] = __builtin_amdgcn_mfma_f32_16x16x32_bf16(af0, bg, acc[0][fj], 0, 0, 0);
      acc[1][fj] = __builtin_amdgcn_mfma_f32_16x16x32_bf16(af1, bg, acc[1][fj], 0, 0, 0);
    }
    asm volatile("s_waitcnt vmcnt(0)" ::: "memory");
    __syncthreads();
  }

  // ---- masked softmax over t (full 512 per j-row); acc IS cosine sim ----
  const int len = lens[b];
  const int q  = gr;
  const int tl = rl;
  const float NEGINF = -__builtin_inff();

  float mx[2][4];
#pragma unroll
  for (int fi = 0; fi < 2; fi++)
#pragma unroll
    for (int rr = 0; rr < 4; rr++) mx[fi][rr] = NEGINF;

#pragma unroll
  for (int fi = 0; fi < 2; fi++)
#pragma unroll
    for (int fj = 0; fj < 8; fj++){
      int t = wt*128 + fj*16 + tl;
      bool ok = t < len;
#pragma unroll
      for (int rr = 0; rr < 4; rr++){
        float v = ok ? acc[fi][fj][rr] : NEGINF;
        acc[fi][fj][rr] = v;
        mx[fi][rr] = fmaxf(mx[fi][rr], v);
      }
    }
#pragma unroll
  for (int fi = 0; fi < 2; fi++)
#pragma unroll
    for (int rr = 0; rr < 4; rr++)
#pragma unroll
      for (int msk = 1; msk <= 8; msk <<= 1)
        mx[fi][rr] = fmaxf(mx[fi][rr], __shfl_xor(mx[fi][rr], msk, 64));
  if (tl == 0){
#pragma unroll
    for (int fi = 0; fi < 2; fi++)
#pragma unroll
      for (int rr = 0; rr < 4; rr++)
        redM[(wj*32 + fi*16 + q*4 + rr)*4 + wt] = mx[fi][rr];
  }
  __syncthreads();

  float gmx[2][4], sum[2][4];
#pragma unroll
  for (int fi = 0; fi < 2; fi++)
#pragma unroll
    for (int rr = 0; rr < 4; rr++){
      int jl = wj*32 + fi*16 + q*4 + rr;
      gmx[fi][rr] = fmaxf(fmaxf(redM[jl*4+0], redM[jl*4+1]),
                          fmaxf(redM[jl*4+2], redM[jl*4+3]));
      sum[fi][rr] = 0.f;
    }
#pragma unroll
  for (int fi = 0; fi < 2; fi++)
#pragma unroll
    for (int fj = 0; fj < 8; fj++)
#pragma unroll
      for (int rr = 0; rr < 4; rr++){
        float e = __expf(acc[fi][fj][rr] - gmx[fi][rr]);  // exp(-inf)=0 for masked
        acc[fi][fj][rr] = e;
        sum[fi][rr] += e;
      }
#pragma unroll
  for (int fi = 0; fi < 2; fi++)
#pragma unroll
    for (int rr = 0; rr < 4; rr++)
#pragma unroll
      for (int msk = 1; msk <= 8; msk <<= 1)
        sum[fi][rr] += __shfl_xor(sum[fi][rr], msk, 64);
  if (tl == 0){
#pragma unroll
    for (int fi = 0; fi < 2; fi++)
#pragma unroll
      for (int rr = 0; rr < 4; rr++)
        redS[(wj*32 + fi*16 + q*4 + rr)*4 + wt] = sum[fi][rr];
  }
  __syncthreads();

#pragma unroll
  for (int fi = 0; fi < 2; fi++)
#pragma unroll
    for (int rr = 0; rr < 4; rr++){
      int jl = wj*32 + fi*16 + q*4 + rr;
      float tot = (redS[jl*4+0] + redS[jl*4+1]) + (redS[jl*4+2] + redS[jl*4+3]);
      float iv = 1.0f / tot;
      int j = jt + jl;
      float* orow = out0 + ((size_t)b*NB + j)*NT + wt*128 + tl;
#pragma unroll
      for (int fj = 0; fj < 8; fj++)
        orow[fj*16] = acc[fi][fj][rr]*iv;
    }
}

// argmax over valid t of diag (first-index tie-break) + copy chosen frame row
__global__ __launch_bounds__(256) void k_argmax(const float* __restrict__ video,
                                                const int* __restrict__ lens,
                                                const float* __restrict__ diag,
                                                float* __restrict__ o1){
  int b = blockIdx.x;
  int tid = threadIdx.x;
  int len = lens[b];
  __shared__ float sv[256];
  __shared__ int   si[256];
  const float* dg = diag + (size_t)b * NT;
  float v1 = (tid       < len) ? dg[tid]       : -__builtin_inff();
  float v2 = (tid + 256 < len) ? dg[tid + 256] : -__builtin_inff();
  float bv; int bi;
  if (v2 > v1){ bv = v2; bi = tid + 256; } else { bv = v1; bi = tid; }
  sv[tid] = bv; si[tid] = bi;
  __syncthreads();
  for (int sN = 128; sN > 0; sN >>= 1){
    if (tid < sN){
      float ov = sv[tid+sN]; int oi = si[tid+sN];
      if (ov > sv[tid] || (ov == sv[tid] && oi < si[tid])){ sv[tid] = ov; si[tid] = oi; }
    }
    __syncthreads();
  }
  int best = si[0];
  const float* src = video + ((size_t)b * NT + best) * ND;
  o1[(size_t)b * ND + tid]       = src[tid];
  o1[(size_t)b * ND + tid + 256] = src[tid + 256];
}

extern "C" void kernel_launch(void* const* d_in, const int* in_sizes, int n_in,
                              void* d_out, int out_size, void* d_ws, size_t ws_size,
                              hipStream_t stream){
  const float* video = (const float*)d_in[0];
  const float* sent  = (const float*)d_in[1];
  const int*   lens  = (const int*)d_in[2];
  float* out0 = (float*)d_out;
  float* out1 = out0 + (size_t)NB*NB*NT;

  char* ws = (char*)d_ws;
  unsigned short* sb   = (unsigned short*)ws;          // 262144 B
  float* sinv  = (float*)(ws + 262144);                // 1024 B
  float* diagw = (float*)(ws + 263168);                // 524288 B
  unsigned short* vb16 = (unsigned short*)(ws + 1048576); // 134217728 B

  k_sent   <<<NB/4,    256, 0, stream>>>(sent, sb, sinv);
  k_vnorm  <<<NB*NT/4, 256, 0, stream>>>(video, sent, sinv, vb16, diagw);
  k_gemm_sm<<<NB*4,    512, 0, stream>>>(sb, vb16, lens, out0);
  k_argmax <<<NB,      256, 0, stream>>>(video, lens, diagw, out1);
}